// Round 1
// baseline (208.790 us; speedup 1.0000x reference)
//
#include <hip/hip_runtime.h>
#include <math.h>

// QClassifier fused kernel, round 6 — persistent double-buffered streaming.
// Math (verified passing since R1, unchanged from R5):
//  - RZ phases are unit-modulus -> cannot affect |state|^2. Dropped.
//  - RY is orthogonal -> probs_k = (V x)_k^2 / ||x||^2; 1/||x||^2 folded into MLP.
//  - Z/ZZ signs are Walsh functions -> 16-pt FWHT of y^2 gives all 10 features;
//    Walsh coeff 0 == ||x||^2, so no separate norm pass.
// Structure (R6) — the kernel was at ~3 TB/s (half of achievable):
//  - Persistent grid-stride blocks, LDS double-buffered (2 x 16 KiB).
//  - global_load_lds width=16: HBM -> LDS directly, zero VGPR staging,
//    zero ds_write instructions. Loads for tile t+1 are issued BEFORE the
//    compute of tile t; the compiler's full vmcnt(0) drain at __syncthreads
//    then lands AFTER ~1500 cy of compute -> HBM latency fully hidden, each
//    block always has one 16 KiB tile in flight (5 blocks/CU = 80 KiB/CU).
//  - global_load_lds writes LDS linearly (wave-uniform base + lane*16), so
//    PAD=20 is impossible. Instead: linear LDS + XOR-swizzled GLOBAL source,
//      slot n <- global float4 g(n) = (n&~3) | ((n&3) ^ ((n>>3)&3)),
//    which permutes only within each 64B line (coalescing identical to R5:
//    16 lines/instr). Read side: thread t reads quarter q at slot
//    4t + (q ^ ((t>>1)&3)) -> 8 consecutive lanes' b128 reads tile all 32
//    banks exactly (same conflict-free property as PAD=20, checked by hand).
//  - cos/sin via readfirstlane -> SGPRs; sCS LDS broadcast removed.
//  - LDS = 32 KiB/block -> 5 blocks/CU, 20 waves/CU; VGPR is not the cap.

#define TPB 256

__device__ __forceinline__ void async_ld16(const float4* g, float4* l) {
    __builtin_amdgcn_global_load_lds(
        (const __attribute__((address_space(1))) void*)g,
        (__attribute__((address_space(3))) void*)l,
        16 /*bytes, literal*/, 0 /*offset*/, 0 /*aux*/);
}

__global__ __launch_bounds__(TPB) void qc_fused(
    const float* __restrict__ x, const float* __restrict__ uw,
    const float* __restrict__ w1, const float* __restrict__ b1,
    const float* __restrict__ w2, const float* __restrict__ b2,
    float* __restrict__ out, long batch)
{
    __shared__ float4 sX[2][1024];   // 2 x 16 KiB, linear layout (slot n = 16B)

    const int t = threadIdx.x;
    const long ntiles = (batch + TPB - 1) >> 8;
    const long nv4 = batch * 4;                 // total float4s in x
    const float4* __restrict__ xv4 = (const float4*)x;

    // ---- uniform gate params -> SGPRs (phi column provably irrelevant) ----
    float cs[4], sn[4];
#pragma unroll
    for (int q = 0; q < 4; ++q) {
        float th = 0.5f * uw[2 * q];
        cs[q] = __uint_as_float(__builtin_amdgcn_readfirstlane(__float_as_uint(cosf(th))));
        sn[q] = __uint_as_float(__builtin_amdgcn_readfirstlane(__float_as_uint(sinf(th))));
    }

    // stage one 256-sample tile (1024 float4) into dst via async HBM->LDS.
    // Source index is pre-swizzled so the linear LDS write realizes the
    // bank-conflict-free read layout. OOB lanes clamp to 0 (store-guarded).
    auto stage = [&](long base4, float4* dst) {
#pragma unroll
        for (int r = 0; r < 4; ++r) {
            int n = (r << 8) + t;
            int gsw = (n & ~3) | ((n & 3) ^ ((n >> 3) & 3));
            long g = base4 + gsw;
            g = (g < nv4) ? g : 0;
            async_ld16(xv4 + g, dst + n);
        }
    };

    long tile = blockIdx.x;
    int cur = 0;
    if (tile < ntiles) stage(tile << 10, &sX[0][0]);
    __syncthreads();                 // drains prologue loads (vmcnt(0) at barrier)

    const int pq = (t >> 1) & 3;     // per-thread quarter permutation

    for (; tile < ntiles; tile += gridDim.x) {
        const long nxt = tile + gridDim.x;
        if (nxt < ntiles) stage(nxt << 10, &sX[cur ^ 1][0]);  // prefetch, in flight
                                                              // through the compute

        // ---- per-thread sample readback (4x ds_read_b128, conflict-free) ----
        const float4* my = &sX[cur][t << 2];
        float y[16];
#pragma unroll
        for (int q = 0; q < 4; ++q) {
            float4 v = my[q ^ pq];   // quarter q lives at slot 4t + (q^pq)
            y[4 * q + 0] = v.x; y[4 * q + 1] = v.y;
            y[4 * q + 2] = v.z; y[4 * q + 3] = v.w;
        }

        // 4 rounds of RY 2x2 rotations; qubit q acts on bit (3-q) (wire0 = MSB)
#pragma unroll
        for (int q = 0; q < 4; ++q) {
            const int st = 8 >> q;
#pragma unroll
            for (int i = 0; i < 16; ++i) {
                if ((i & st) == 0) {
                    float a = y[i], b = y[i + st];
                    y[i]      = fmaf(cs[q], a, -sn[q] * b);
                    y[i + st] = fmaf(sn[q], a,  cs[q] * b);
                }
            }
        }

        // squares then in-place FWHT (unused Walsh outputs DCE'd by compiler)
        float p[16];
#pragma unroll
        for (int i = 0; i < 16; ++i) p[i] = y[i] * y[i];
#pragma unroll
        for (int st = 1; st < 16; st <<= 1) {
#pragma unroll
            for (int i = 0; i < 16; ++i) {
                if ((i & st) == 0) {
                    float a = p[i], b = p[i + st];
                    p[i]      = a + b;
                    p[i + st] = a - b;
                }
            }
        }

        const float rn = 1.0f / p[0];     // p[0] = ||x||^2

        // features: z0..z3 -> Walsh masks 8,4,2,1 ; zz(i<j) -> 12,10,9,6,5,3
        constexpr int bmap[10] = {8, 4, 2, 1, 12, 10, 9, 6, 5, 3};

        float tacc[16];
#pragma unroll
        for (int j = 0; j < 16; ++j) tacc[j] = 0.f;
#pragma unroll
        for (int f = 0; f < 10; ++f) {
            const float pf = p[bmap[f]];
#pragma unroll
            for (int j = 0; j < 16; ++j)
                tacc[j] = fmaf(w1[j * 10 + f], pf, tacc[j]);   // uniform -> s_load
        }

        float o0 = b2[0], o1 = b2[1];
#pragma unroll
        for (int j = 0; j < 16; ++j) {
            float h = fmaxf(fmaf(tacc[j], rn, b1[j]), 0.f);    // uniform -> s_load
            o0 = fmaf(w2[j],      h, o0);
            o1 = fmaf(w2[16 + j], h, o1);
        }

        const long sidx = (tile << 8) + t;
        if (sidx < batch) ((float2*)out)[sidx] = make_float2(o0, o1);

        __syncthreads();   // drains nxt's async loads (after compute overlap)
                           // + protects buf[cur] before it is re-staged
        cur ^= 1;
    }
}

extern "C" void kernel_launch(void* const* d_in, const int* in_sizes, int n_in,
                              void* d_out, int out_size, void* d_ws, size_t ws_size,
                              hipStream_t stream) {
    const float* x  = (const float*)d_in[0];
    const float* uw = (const float*)d_in[1];
    const float* w1 = (const float*)d_in[2];
    const float* b1 = (const float*)d_in[3];
    const float* w2 = (const float*)d_in[4];
    const float* b2 = (const float*)d_in[5];
    float* out = (float*)d_out;

    long batch = (long)(in_sizes[0] / 16);
    long ntiles = (batch + 255) / 256;
    // 5 blocks/CU by LDS (32 KiB each) x 256 CUs = 1280 persistent blocks
    long blocks = ntiles < 1280 ? ntiles : 1280;
    hipLaunchKernelGGL(qc_fused, dim3((unsigned)blocks), dim3(256), 0, stream,
                       x, uw, w1, b1, w2, b2, out, batch);
}